// Round 1
// baseline (749.673 us; speedup 1.0000x reference)
//
#include <hip/hip_runtime.h>
#include <hip/hip_bf16.h>

#define HEADS 4
#define ODIM 64
#define HD 256          // HEADS*ODIM
#define NEG_SLOPE 0.2f

// ---------------- GEMM: h = x @ W  (M x K) @ (K x N), fp32 ----------------
#define TM 64
#define TN 64
#define TK 16

__global__ __launch_bounds__(256) void gemm_xw(const float* __restrict__ A,
                                               const float* __restrict__ B,
                                               float* __restrict__ C,
                                               int M, int N, int K) {
    __shared__ float As[TK][68];   // [k][m], stride 68 to spread store banks
    __shared__ float Bs[TK][TN];   // [k][n]
    const int tid = threadIdx.x;
    const int bm = blockIdx.y * TM;
    const int bn = blockIdx.x * TN;
    const int ty = tid >> 4, tx = tid & 15;

    float acc[4][4] = {};

    for (int k0 = 0; k0 < K; k0 += TK) {
        // A tile 64x16: thread -> row m = tid>>2, k-group (tid&3)*4
        {
            const int m = tid >> 2, kg = (tid & 3) * 4;
            const float4 av = *(const float4*)&A[(size_t)(bm + m) * K + k0 + kg];
            As[kg + 0][m] = av.x; As[kg + 1][m] = av.y;
            As[kg + 2][m] = av.z; As[kg + 3][m] = av.w;
            // B tile 16x64
            const int kb = tid >> 4, nb = (tid & 15) * 4;
            *(float4*)&Bs[kb][nb] = *(const float4*)&B[(size_t)(k0 + kb) * N + bn + nb];
        }
        __syncthreads();
        #pragma unroll
        for (int kk = 0; kk < TK; ++kk) {
            const float4 a4 = *(const float4*)&As[kk][ty * 4];
            const float4 b4 = *(const float4*)&Bs[kk][tx * 4];
            const float a[4] = {a4.x, a4.y, a4.z, a4.w};
            const float b[4] = {b4.x, b4.y, b4.z, b4.w};
            #pragma unroll
            for (int i = 0; i < 4; ++i)
                #pragma unroll
                for (int j = 0; j < 4; ++j)
                    acc[i][j] = fmaf(a[i], b[j], acc[i][j]);
        }
        __syncthreads();
    }
    #pragma unroll
    for (int i = 0; i < 4; ++i) {
        float4 v = {acc[i][0], acc[i][1], acc[i][2], acc[i][3]};
        *(float4*)&C[(size_t)(bm + ty * 4 + i) * N + bn + tx * 4] = v;
    }
}

// ---- per-(node,head): E = {exp(e_src), exp(.2 e_src), exp(e_dst), exp(.2 e_dst)} ----
__global__ __launch_bounds__(256) void calc_e(const float* __restrict__ h,
                                              const float* __restrict__ att,
                                              float4* __restrict__ E, int n) {
    const int i = blockIdx.x;
    const int hh = threadIdx.x >> 6, d = threadIdx.x & 63;
    const float v = h[(size_t)i * HD + hh * ODIM + d];
    float ps = v * att[hh * 2 * ODIM + d];
    float pd = v * att[hh * 2 * ODIM + ODIM + d];
    #pragma unroll
    for (int m = 32; m >= 1; m >>= 1) {
        ps += __shfl_xor(ps, m, 64);
        pd += __shfl_xor(pd, m, 64);
    }
    if (d == 0) {
        E[i * HEADS + hh] = make_float4(__expf(ps), __expf(NEG_SLOPE * ps),
                                        __expf(pd), __expf(NEG_SLOPE * pd));
    }
}

// ---------------- aggregation: out[i,h,d] = sum_j w(i,j,h) h[j,h,d] / den ----------------
#define AGG_I 16
#define AGG_JC 64

__global__ __launch_bounds__(256) void aggregate(const float* __restrict__ hmat,
                                                 const int* __restrict__ adj,
                                                 const float4* __restrict__ E,
                                                 float* __restrict__ out, int n) {
    __shared__ float ws[AGG_I][HEADS][AGG_JC];   // 16 KiB
    __shared__ float dsh[AGG_I][HEADS];

    const int tid = threadIdx.x;
    const int i0 = blockIdx.x * AGG_I;
    const int hw = tid >> 6;      // head for this wave (uniform per wave)
    const int jw = tid & 63;      // lane -> local j in w-phase

    float acc[AGG_I];
    float den[AGG_I];
    #pragma unroll
    for (int i = 0; i < AGG_I; ++i) { acc[i] = 0.f; den[i] = 0.f; }

    // preload src-side exps for the 16 rows of this tile (head hw)
    float es1[AGG_I], es2[AGG_I];
    #pragma unroll
    for (int i = 0; i < AGG_I; ++i) {
        const float4 e = E[(i0 + i) * HEADS + hw];
        es1[i] = e.x; es2[i] = e.y;
    }

    for (int jc = 0; jc < n; jc += AGG_JC) {
        // ---- w-phase: build weight tile [i][head][j] in LDS ----
        const float4 ed = E[(jc + jw) * HEADS + hw];  // .z/.w = dst exps
        #pragma unroll
        for (int i = 0; i < AGG_I; ++i) {
            const int a = adj[(size_t)(i0 + i) * n + jc + jw];
            const float p1 = es1[i] * ed.z;            // exp(e_src+e_dst)
            const float p2 = es2[i] * ed.w;            // exp(.2*(e_src+e_dst))
            float w = (p1 > 1.0f) ? p1 : p2;           // leaky_relu in exp-domain
            w = (a > 0) ? w : 0.f;
            ws[i][hw][jw] = w;
            den[i] += w;
        }
        __syncthreads();
        // ---- FMA phase: thread t = (head, d) column, 16 row-accumulators ----
        #pragma unroll 2
        for (int jj = 0; jj < AGG_JC; jj += 4) {
            const float hv0 = hmat[(size_t)(jc + jj + 0) * HD + tid];
            const float hv1 = hmat[(size_t)(jc + jj + 1) * HD + tid];
            const float hv2 = hmat[(size_t)(jc + jj + 2) * HD + tid];
            const float hv3 = hmat[(size_t)(jc + jj + 3) * HD + tid];
            #pragma unroll
            for (int i = 0; i < AGG_I; ++i) {
                const float4 w4 = *(const float4*)&ws[i][hw][jj];
                acc[i] = fmaf(w4.x, hv0, acc[i]);
                acc[i] = fmaf(w4.y, hv1, acc[i]);
                acc[i] = fmaf(w4.z, hv2, acc[i]);
                acc[i] = fmaf(w4.w, hv3, acc[i]);
            }
        }
        __syncthreads();
    }

    // ---- reduce denominators across the wave's 64 j-lanes ----
    #pragma unroll
    for (int i = 0; i < AGG_I; ++i) {
        float d = den[i];
        #pragma unroll
        for (int m = 32; m >= 1; m >>= 1) d += __shfl_xor(d, m, 64);
        if (jw == 0) dsh[i][hw] = d;
    }
    __syncthreads();

    #pragma unroll
    for (int i = 0; i < AGG_I; ++i) {
        const float d = dsh[i][hw];
        out[(size_t)(i0 + i) * HD + tid] = acc[i] / d;
    }
}

extern "C" void kernel_launch(void* const* d_in, const int* in_sizes, int n_in,
                              void* d_out, int out_size, void* d_ws, size_t ws_size,
                              hipStream_t stream) {
    const float* x   = (const float*)d_in[0];
    const int*   adj = (const int*)d_in[1];
    const float* W   = (const float*)d_in[2];
    const float* att = (const float*)d_in[3];
    float* out = (float*)d_out;

    const int in_dim = in_sizes[2] / HD;         // 256
    const int n = in_sizes[0] / in_dim;          // 4096

    float*  h = (float*)d_ws;                                   // n*HD fp32 = 4 MiB
    float4* E = (float4*)((char*)d_ws + (size_t)n * HD * 4);    // n*HEADS float4

    gemm_xw<<<dim3(HD / TN, n / TM), 256, 0, stream>>>(x, W, h, n, HD, in_dim);
    calc_e<<<n, 256, 0, stream>>>(h, att, E, n);
    aggregate<<<n / AGG_I, 256, 0, stream>>>(h, adj, E, out, n);
}

// Round 2
// 196.605 us; speedup vs baseline: 3.8131x; 3.8131x over previous
//
#include <hip/hip_runtime.h>
#include <hip/hip_bf16.h>

#define HEADS 4
#define ODIM 64
#define HD 256          // HEADS*ODIM
#define NEG_SLOPE 0.2f
#define JSTRIDE 4224    // 4096 + 128: breaks L2-channel aliasing of stride-8KB B-frag reads

typedef __attribute__((ext_vector_type(8))) short bf16x8;
typedef __attribute__((ext_vector_type(4))) float floatx4;

// ---------------- GEMM: h = x @ W  (fp32, unchanged from R1) ----------------
#define TM 64
#define TN 64
#define TK 16

__global__ __launch_bounds__(256) void gemm_xw(const float* __restrict__ A,
                                               const float* __restrict__ B,
                                               float* __restrict__ C,
                                               int M, int N, int K) {
    __shared__ float As[TK][68];
    __shared__ float Bs[TK][TN];
    const int tid = threadIdx.x;
    const int bm = blockIdx.y * TM;
    const int bn = blockIdx.x * TN;
    const int ty = tid >> 4, tx = tid & 15;

    float acc[4][4] = {};

    for (int k0 = 0; k0 < K; k0 += TK) {
        {
            const int m = tid >> 2, kg = (tid & 3) * 4;
            const float4 av = *(const float4*)&A[(size_t)(bm + m) * K + k0 + kg];
            As[kg + 0][m] = av.x; As[kg + 1][m] = av.y;
            As[kg + 2][m] = av.z; As[kg + 3][m] = av.w;
            const int kb = tid >> 4, nb = (tid & 15) * 4;
            *(float4*)&Bs[kb][nb] = *(const float4*)&B[(size_t)(k0 + kb) * N + bn + nb];
        }
        __syncthreads();
        #pragma unroll
        for (int kk = 0; kk < TK; ++kk) {
            const float4 a4 = *(const float4*)&As[kk][ty * 4];
            const float4 b4 = *(const float4*)&Bs[kk][tx * 4];
            const float a[4] = {a4.x, a4.y, a4.z, a4.w};
            const float b[4] = {b4.x, b4.y, b4.z, b4.w};
            #pragma unroll
            for (int i = 0; i < 4; ++i)
                #pragma unroll
                for (int j = 0; j < 4; ++j)
                    acc[i][j] = fmaf(a[i], b[j], acc[i][j]);
        }
        __syncthreads();
    }
    #pragma unroll
    for (int i = 0; i < 4; ++i) {
        float4 v = {acc[i][0], acc[i][1], acc[i][2], acc[i][3]};
        *(float4*)&C[(size_t)(bm + ty * 4 + i) * N + bn + tx * 4] = v;
    }
}

// ---- per-(node,head): E = {exp(e_src), exp(.2 e_src), exp(e_dst), exp(.2 e_dst)} ----
__global__ __launch_bounds__(256) void calc_e(const float* __restrict__ h,
                                              const float* __restrict__ att,
                                              float4* __restrict__ E, int n) {
    const int i = blockIdx.x;
    const int hh = threadIdx.x >> 6, d = threadIdx.x & 63;
    const float v = h[(size_t)i * HD + hh * ODIM + d];
    float ps = v * att[hh * 2 * ODIM + d];
    float pd = v * att[hh * 2 * ODIM + ODIM + d];
    #pragma unroll
    for (int m = 32; m >= 1; m >>= 1) {
        ps += __shfl_xor(ps, m, 64);
        pd += __shfl_xor(pd, m, 64);
    }
    if (d == 0) {
        E[i * HEADS + hh] = make_float4(__expf(ps), __expf(NEG_SLOPE * ps),
                                        __expf(pd), __expf(NEG_SLOPE * pd));
    }
}

// ---- transpose h (fp32 [n][256]) -> hbT (bf16 [4][64][JSTRIDE]) ----
__global__ __launch_bounds__(256) void transpose_h(const float* __restrict__ h,
                                                   __hip_bfloat16* __restrict__ hbT, int n) {
    __shared__ __hip_bfloat16 T[64][66];  // 66: 2-way max bank aliasing on transposed read
    const int j0 = blockIdx.x * 64;
    const int hh = blockIdx.y;
    const int c = threadIdx.x & 63, rr = threadIdx.x >> 6;
    #pragma unroll
    for (int k = 0; k < 16; ++k) {
        const int jr = rr * 16 + k;
        T[jr][c] = __float2bfloat16(h[(size_t)(j0 + jr) * HD + hh * ODIM + c]);
    }
    __syncthreads();
    const int j = threadIdx.x & 63, dd = threadIdx.x >> 6;
    #pragma unroll
    for (int k = 0; k < 16; ++k) {
        const int d = dd * 16 + k;
        hbT[(size_t)(hh * ODIM + d) * JSTRIDE + j0 + j] = T[j][d];
    }
}

// ---------------- MFMA aggregation: out[i, h*64+d] += sum_j P[i,j,h] hb[j,h,d] ----------------
// block: 256 thr = 4 waves (wave = head). i-tile 16, j-chunk 64, K split 4-way across blockIdx.y.
#define BI 16
#define BJ 64
#define SPLITS 4

__global__ __launch_bounds__(256) void aggregate_mfma(
    const int* __restrict__ adj, const float4* __restrict__ E,
    const __hip_bfloat16* __restrict__ hbT, float* __restrict__ out,
    float* __restrict__ den, int n) {

    __shared__ __hip_bfloat16 Pt[HEADS][BI][BJ + 8];  // A-tiles, pad 64->72 (2-way banks on b128)
    __shared__ float2 EdL[HEADS][BJ];                 // dst-side exps for the chunk

    const int tid = threadIdx.x;
    const int wave = tid >> 6, lane = tid & 63;
    const int q = lane >> 4, l16 = lane & 15;
    const int i0 = blockIdx.x * BI;
    const int KR = n / SPLITS;
    const int K0 = blockIdx.y * KR;

    // P-build mapping: thread -> (row bi, 4 consecutive j), all 4 heads
    const int bi = tid >> 4;
    const int jg = (tid & 15) * 4;
    // EdL-stage mapping
    const int je = tid >> 2, he = tid & 3;

    float es1[HEADS], es2[HEADS];
    #pragma unroll
    for (int h = 0; h < HEADS; ++h) {
        const float4 e = E[(i0 + bi) * HEADS + h];
        es1[h] = e.x; es2[h] = e.y;
    }

    floatx4 acc[4] = {{0.f,0.f,0.f,0.f},{0.f,0.f,0.f,0.f},{0.f,0.f,0.f,0.f},{0.f,0.f,0.f,0.f}};
    float denp[HEADS] = {0.f, 0.f, 0.f, 0.f};

    for (int jc = K0; jc < K0 + KR; jc += BJ) {
        // ---- stage EdL (coalesced float4 read of E) ----
        const float4 ev = E[(jc + je) * HEADS + he];
        EdL[he][je] = make_float2(ev.z, ev.w);
        __syncthreads();   // EdL ready; prev-iter Pt reads retired

        // ---- build P-tile (exp-domain leaky-relu weights), bf16 ----
        const int4 a4 = *(const int4*)&adj[(size_t)(i0 + bi) * n + jc + jg];
        const int am[4] = {a4.x, a4.y, a4.z, a4.w};
        #pragma unroll
        for (int h = 0; h < HEADS; ++h) {
            const float4 ed01 = *(const float4*)&EdL[h][jg];      // {z0,w0,z1,w1}
            const float4 ed23 = *(const float4*)&EdL[h][jg + 2];  // {z2,w2,z3,w3}
            const float edz[4] = {ed01.x, ed01.z, ed23.x, ed23.z};
            const float edw[4] = {ed01.y, ed01.w, ed23.y, ed23.w};
            union { __hip_bfloat16 b[4]; uint2 u; } pk;
            #pragma unroll
            for (int j = 0; j < 4; ++j) {
                const float p1 = es1[h] * edz[j];   // exp(e_src+e_dst)
                const float p2 = es2[h] * edw[j];   // exp(.2*(e_src+e_dst))
                float w = (p1 > 1.0f) ? p1 : p2;    // leaky_relu in exp domain
                w = (am[j] > 0) ? w : 0.0f;
                pk.b[j] = __float2bfloat16(w);
                denp[h] += __bfloat162float(pk.b[j]); // den from the rounded value
            }
            *(uint2*)&Pt[h][bi][jg] = pk.u;
        }
        __syncthreads();   // Pt ready

        // ---- MFMA: wave = head; A = Pt (16i x 64j), B = hbT (64j x 64d) ----
        const __hip_bfloat16* bbase = hbT + (size_t)(wave * ODIM) * JSTRIDE + jc + q * 8;
        #pragma unroll
        for (int ks = 0; ks < 2; ++ks) {
            const bf16x8 af = *(const bf16x8*)&Pt[wave][l16][ks * 32 + q * 8];
            #pragma unroll
            for (int nt = 0; nt < 4; ++nt) {
                const bf16x8 bf = *(const bf16x8*)&bbase[(size_t)(nt * 16 + l16) * JSTRIDE + ks * 32];
                acc[nt] = __builtin_amdgcn_mfma_f32_16x16x32_bf16(af, bf, acc[nt], 0, 0, 0);
            }
        }
    }

    // ---- den: reduce across the 16 j-group threads sharing bi, then atomic ----
    #pragma unroll
    for (int h = 0; h < HEADS; ++h) {
        float d = denp[h];
        d += __shfl_xor(d, 1, 64);
        d += __shfl_xor(d, 2, 64);
        d += __shfl_xor(d, 4, 64);
        d += __shfl_xor(d, 8, 64);
        if ((tid & 15) == 0) atomicAdd(&den[(i0 + bi) * HEADS + h], d);
    }

    // ---- out: C-frag row = q*4+reg, col = l16 (+16*nt), head = wave ----
    #pragma unroll
    for (int nt = 0; nt < 4; ++nt) {
        #pragma unroll
        for (int r = 0; r < 4; ++r) {
            const int row = i0 + q * 4 + r;
            const int col = wave * ODIM + nt * 16 + l16;
            atomicAdd(&out[(size_t)row * HD + col], acc[nt][r]);
        }
    }
}

// ---------------- normalize: out /= den ----------------
__global__ __launch_bounds__(256) void normalize(float* __restrict__ out,
                                                 const float* __restrict__ den, int n) {
    const int t = blockIdx.x * blockDim.x + threadIdx.x;
    const int i = t >> 6;
    const int c4 = (t & 63) * 4;
    const float inv = 1.0f / den[i * HEADS + (c4 >> 6)];
    float4 v = *(float4*)&out[(size_t)i * HD + c4];
    v.x *= inv; v.y *= inv; v.z *= inv; v.w *= inv;
    *(float4*)&out[(size_t)i * HD + c4] = v;
}

extern "C" void kernel_launch(void* const* d_in, const int* in_sizes, int n_in,
                              void* d_out, int out_size, void* d_ws, size_t ws_size,
                              hipStream_t stream) {
    const float* x   = (const float*)d_in[0];
    const int*   adj = (const int*)d_in[1];
    const float* W   = (const float*)d_in[2];
    const float* att = (const float*)d_in[3];
    float* out = (float*)d_out;

    const int in_dim = in_sizes[2] / HD;         // 256
    const int n = in_sizes[0] / in_dim;          // 4096

    // workspace layout (~6.6 MB)
    char* ws = (char*)d_ws;
    float*  h   = (float*)ws;                                  // n*HD fp32   = 4 MiB
    float4* E   = (float4*)(ws + (size_t)n * HD * 4);          // n*HEADS f4  = 256 KiB
    __hip_bfloat16* hbT = (__hip_bfloat16*)(ws + (size_t)n * HD * 4 + (size_t)n * HEADS * 16);
    float*  den = (float*)((char*)hbT + (size_t)HEADS * ODIM * JSTRIDE * 2);

    hipMemsetAsync(out, 0, (size_t)n * HD * 4, stream);
    hipMemsetAsync(den, 0, (size_t)n * HEADS * 4, stream);

    gemm_xw<<<dim3(HD / TN, n / TM), 256, 0, stream>>>(x, W, h, n, HD, in_dim);
    calc_e<<<n, 256, 0, stream>>>(h, att, E, n);
    transpose_h<<<dim3(n / 64, HEADS), 256, 0, stream>>>(h, hbT, n);
    aggregate_mfma<<<dim3(n / BI, SPLITS), 256, 0, stream>>>(adj, E, hbT, out, den, n);
    normalize<<<(n * ODIM) / 256, 256, 0, stream>>>(out, den, n);
}

// Round 3
// 147.448 us; speedup vs baseline: 5.0843x; 1.3334x over previous
//
#include <hip/hip_runtime.h>
#include <hip/hip_bf16.h>

#define HEADS 4
#define ODIM 64
#define HD 256          // HEADS*ODIM
#define NEG_SLOPE 0.2f

typedef __attribute__((ext_vector_type(8))) short bf16x8;
typedef __attribute__((ext_vector_type(4))) float floatx4;

// ============ pack x -> bf16 hi/lo MFMA A-fragments ============
// layout: frag[(mc*Kc + kc)][lane][8], lane=(l16,q): A[m=mc*16+l16][k=kc*32+q*8+p]
__global__ __launch_bounds__(256) void pack_x(const float* __restrict__ x,
                                              __hip_bfloat16* __restrict__ xh,
                                              __hip_bfloat16* __restrict__ xl, int K) {
    const int g = blockIdx.x * 256 + threadIdx.x;
    const int lane = g & 63, frag = g >> 6;
    const int Kc = K >> 5;
    const int kc = frag % Kc, mc = frag / Kc;
    const int l16 = lane & 15, q = lane >> 4;
    const float* src = x + (size_t)(mc * 16 + l16) * K + kc * 32 + q * 8;
    const float4 v0 = *(const float4*)src;
    const float4 v1 = *(const float4*)(src + 4);
    const float vv[8] = {v0.x, v0.y, v0.z, v0.w, v1.x, v1.y, v1.z, v1.w};
    union { __hip_bfloat16 b[8]; bf16x8 v; } H, L;
    #pragma unroll
    for (int p = 0; p < 8; ++p) {
        H.b[p] = __float2bfloat16(vv[p]);
        L.b[p] = __float2bfloat16(vv[p] - __bfloat162float(H.b[p]));
    }
    *(bf16x8*)&xh[(size_t)frag * 512 + lane * 8] = H.v;
    *(bf16x8*)&xl[(size_t)frag * 512 + lane * 8] = L.v;
}

// ============ pack W -> bf16 hi/lo MFMA B-fragments ============
// layout: frag[(nc*Kc + kc)][lane][8], lane=(l16,q): B[k=kc*32+q*8+p][n=nc*16+l16]
__global__ __launch_bounds__(256) void pack_w(const float* __restrict__ W,
                                              __hip_bfloat16* __restrict__ wh,
                                              __hip_bfloat16* __restrict__ wl,
                                              int N, int K) {
    const int g = blockIdx.x * 256 + threadIdx.x;
    const int lane = g & 63, frag = g >> 6;
    const int Kc = K >> 5;
    const int kc = frag % Kc, nc = frag / Kc;
    const int l16 = lane & 15, q = lane >> 4;
    union { __hip_bfloat16 b[8]; bf16x8 v; } H, L;
    #pragma unroll
    for (int p = 0; p < 8; ++p) {
        const float w = W[(size_t)(kc * 32 + q * 8 + p) * N + nc * 16 + l16];
        H.b[p] = __float2bfloat16(w);
        L.b[p] = __float2bfloat16(w - __bfloat162float(H.b[p]));
    }
    *(bf16x8*)&wh[(size_t)frag * 512 + lane * 8] = H.v;
    *(bf16x8*)&wl[(size_t)frag * 512 + lane * 8] = L.v;
}

// ============ fused GEMM: h = x@W (hi/lo bf16 MFMA) + E epilogue + B-frag pack of h ============
// block = (64 rows, 1 head). grid (n/64, HEADS).
__global__ __launch_bounds__(256) void gemm_fused(
    const __hip_bfloat16* __restrict__ xh, const __hip_bfloat16* __restrict__ xl,
    const __hip_bfloat16* __restrict__ wh, const __hip_bfloat16* __restrict__ wl,
    const float* __restrict__ att, float4* __restrict__ E4,
    __hip_bfloat16* __restrict__ hbB, int n, int K) {

    __shared__ __hip_bfloat16 T[64][80];   // h^T tile [d][j], stride 80 (16B-aligned rows)

    const int tid = threadIdx.x, wave = tid >> 6, lane = tid & 63;
    const int q = lane >> 4, l16 = lane & 15;
    const int m0 = blockIdx.x * 64;
    const int head = blockIdx.y;
    const int Kc = K >> 5;
    const int mc = (m0 >> 4) + wave;

    floatx4 acc[4] = {{0.f,0.f,0.f,0.f},{0.f,0.f,0.f,0.f},{0.f,0.f,0.f,0.f},{0.f,0.f,0.f,0.f}};

    const __hip_bfloat16* Ab[3] = {xh, xh, xl};
    const __hip_bfloat16* Bb[3] = {wh, wl, wh};
    #pragma unroll
    for (int pass = 0; pass < 3; ++pass) {
        const __hip_bfloat16* A = Ab[pass] + (size_t)mc * Kc * 512 + lane * 8;
        const __hip_bfloat16* B = Bb[pass] + lane * 8;
        for (int kc = 0; kc < Kc; ++kc) {
            const bf16x8 af = *(const bf16x8*)(A + (size_t)kc * 512);
            #pragma unroll
            for (int nt = 0; nt < 4; ++nt) {
                const bf16x8 bf = *(const bf16x8*)(B + (size_t)((head * 4 + nt) * Kc + kc) * 512);
                acc[nt] = __builtin_amdgcn_mfma_f32_16x16x32_bf16(af, bf, acc[nt], 0, 0, 0);
            }
        }
    }

    // ---- E epilogue: e_src/e_dst row sums via shuffle over the 16-lane group ----
    float as_v[4], ad_v[4];
    #pragma unroll
    for (int nt = 0; nt < 4; ++nt) {
        as_v[nt] = att[head * 2 * ODIM + nt * 16 + l16];
        ad_v[nt] = att[head * 2 * ODIM + ODIM + nt * 16 + l16];
    }
    #pragma unroll
    for (int r = 0; r < 4; ++r) {
        float ps = 0.f, pd = 0.f;
        #pragma unroll
        for (int nt = 0; nt < 4; ++nt) {
            ps = fmaf(acc[nt][r], as_v[nt], ps);
            pd = fmaf(acc[nt][r], ad_v[nt], pd);
        }
        #pragma unroll
        for (int m = 1; m <= 8; m <<= 1) {
            ps += __shfl_xor(ps, m, 64);
            pd += __shfl_xor(pd, m, 64);
        }
        if (l16 == 0) {
            const int i = m0 + wave * 16 + q * 4 + r;
            E4[i * HEADS + head] = make_float4(__expf(ps), __expf(NEG_SLOPE * ps),
                                               __expf(pd), __expf(NEG_SLOPE * pd));
        }
    }

    // ---- write h tile transposed to LDS as bf16 ----
    #pragma unroll
    for (int nt = 0; nt < 4; ++nt) {
        union { __hip_bfloat16 b[4]; uint2 u; } pk;
        #pragma unroll
        for (int r = 0; r < 4; ++r) pk.b[r] = __float2bfloat16(acc[nt][r]);
        *(uint2*)&T[nt * 16 + l16][wave * 16 + q * 4] = pk.u;
    }
    __syncthreads();

    // ---- emit packed B-frags of h: frag[(head*(n/32) + j32)*4 + nt][lane][8] ----
    #pragma unroll
    for (int ffi = 0; ffi < 2; ++ffi) {
        const int ff = (tid >> 6) + ffi * 4;
        const int kcl = ff >> 2, nt = ff & 3;
        const bf16x8 v = *(const bf16x8*)&T[nt * 16 + l16][kcl * 32 + q * 8];
        const size_t frag = ((size_t)head * (n >> 5) + (m0 >> 5) + kcl) * 4 + nt;
        *(bf16x8*)&hbB[frag * 512 + lane * 8] = v;
    }
}

// ============ aggregate: out_split[s][i][h*64+d] = sum_j P[i,j,h] h[j,h,d] ============
// block: 4 waves (wave=head), i-tile 32, j-chunk 64, K split across blockIdx.y.
__global__ __launch_bounds__(256, 4) void aggregate(
    const int* __restrict__ adj, const float4* __restrict__ E4,
    const __hip_bfloat16* __restrict__ hbB, float* __restrict__ outsp,
    float* __restrict__ densp, int n, int KR) {

    __shared__ unsigned short adjL[32][88];   // 0xFFFF / 0 masks, stride 88 (16B-aligned, 2-way banks)
    __shared__ float2 EdL[HEADS][64];         // dst-side exps for the chunk

    const int tid = threadIdx.x;
    const int wave = tid >> 6, lane = tid & 63;
    const int q = lane >> 4, l16 = lane & 15, q8 = (lane >> 4) * 8;
    const int i0 = blockIdx.x * 32;
    const int K0 = blockIdx.y * KR;

    // staging maps
    const int sr = tid >> 3, sg = (tid & 7) * 8;   // adj: 32 rows x 8-int groups
    const int je = tid >> 2, he = tid & 3;         // E:   64 j x 4 heads

    // src-side exps for this lane's two rows (head = wave)
    float es1[2], es2[2];
    #pragma unroll
    for (int mt = 0; mt < 2; ++mt) {
        const float4 e = E4[(i0 + mt * 16 + l16) * HEADS + wave];
        es1[mt] = e.x; es2[mt] = e.y;
    }

    // ones-column B-frag for MFMA-based denominator
    union { short s[8]; bf16x8 v; } bones;
    #pragma unroll
    for (int p = 0; p < 8; ++p) bones.s[p] = (l16 == 0) ? (short)0x3F80 : (short)0;

    floatx4 acc[2][4];
    floatx4 accd[2];
    #pragma unroll
    for (int mt = 0; mt < 2; ++mt) {
        accd[mt] = (floatx4){0.f, 0.f, 0.f, 0.f};
        #pragma unroll
        for (int nt = 0; nt < 4; ++nt) acc[mt][nt] = (floatx4){0.f, 0.f, 0.f, 0.f};
    }

    // software prefetch of next chunk's adj + E
    int4 aj0, aj1; float4 ev;
    {
        const int* ap = &adj[(size_t)(i0 + sr) * n + K0 + sg];
        aj0 = *(const int4*)ap; aj1 = *(const int4*)(ap + 4);
        ev = E4[(K0 + je) * HEADS + he];
    }

    for (int jc = K0; jc < K0 + KR; jc += 64) {
        __syncthreads();   // previous chunk's LDS reads retired
        // ---- stage adj masks + dst exps ----
        {
            const int av[8] = {aj0.x, aj0.y, aj0.z, aj0.w, aj1.x, aj1.y, aj1.z, aj1.w};
            uint4 u;
            u.x = (av[0] > 0 ? 0xFFFFu : 0u) | (av[1] > 0 ? 0xFFFF0000u : 0u);
            u.y = (av[2] > 0 ? 0xFFFFu : 0u) | (av[3] > 0 ? 0xFFFF0000u : 0u);
            u.z = (av[4] > 0 ? 0xFFFFu : 0u) | (av[5] > 0 ? 0xFFFF0000u : 0u);
            u.w = (av[6] > 0 ? 0xFFFFu : 0u) | (av[7] > 0 ? 0xFFFF0000u : 0u);
            *(uint4*)&adjL[sr][sg] = u;
            EdL[he][je] = make_float2(ev.z, ev.w);
        }
        __syncthreads();
        // ---- prefetch next chunk (global; overlaps compute below) ----
        {
            int jn = jc + 64; if (jn >= K0 + KR) jn = K0;   // dummy tail reload
            const int* ap = &adj[(size_t)(i0 + sr) * n + jn + sg];
            aj0 = *(const int4*)ap; aj1 = *(const int4*)(ap + 4);
            ev = E4[(jn + je) * HEADS + he];
        }
        // ---- B-frags (coalesced, L2-resident) ----
        bf16x8 bfr[2][4];
        const size_t kbase = (size_t)wave * (n >> 5) + (jc >> 5);
        #pragma unroll
        for (int ks = 0; ks < 2; ++ks)
            #pragma unroll
            for (int nt = 0; nt < 4; ++nt)
                bfr[ks][nt] = *(const bf16x8*)&hbB[((kbase + ks) * 4 + nt) * 512 + lane * 8];

        // ---- compute ----
        #pragma unroll
        for (int ks = 0; ks < 2; ++ks) {
            const float4* ep = (const float4*)&EdL[wave][ks * 32 + q8];
            const float4 e0 = ep[0], e1 = ep[1], e2 = ep[2], e3 = ep[3];
            const float edz[8] = {e0.x, e0.z, e1.x, e1.z, e2.x, e2.z, e3.x, e3.z};
            const float edw[8] = {e0.y, e0.w, e1.y, e1.w, e2.y, e2.w, e3.y, e3.w};
            #pragma unroll
            for (int mt = 0; mt < 2; ++mt) {
                const uint4 msk = *(const uint4*)&adjL[mt * 16 + l16][ks * 32 + q8];
                const unsigned int mm[4] = {msk.x, msk.y, msk.z, msk.w};
                union { unsigned int u[4]; bf16x8 v; } af;
                #pragma unroll
                for (int p = 0; p < 4; ++p) {
                    // leaky-relu in exp domain: w = max(exp(s), exp(0.2 s)) — exact
                    const float wa = fmaxf(es1[mt] * edz[2 * p],     es2[mt] * edw[2 * p]);
                    const float wb = fmaxf(es1[mt] * edz[2 * p + 1], es2[mt] * edw[2 * p + 1]);
                    union { __hip_bfloat16 b[2]; unsigned int u; } pk;
                    pk.b[0] = __float2bfloat16(wa);
                    pk.b[1] = __float2bfloat16(wb);
                    af.u[p] = pk.u & mm[p];   // adjacency mask
                }
                #pragma unroll
                for (int nt = 0; nt < 4; ++nt)
                    acc[mt][nt] = __builtin_amdgcn_mfma_f32_16x16x32_bf16(af.v, bfr[ks][nt], acc[mt][nt], 0, 0, 0);
                accd[mt] = __builtin_amdgcn_mfma_f32_16x16x32_bf16(af.v, bones.v, accd[mt], 0, 0, 0);
            }
        }
    }

    // ---- epilogue: disjoint per-split writes, no atomics ----
    const size_t sOut = (size_t)blockIdx.y * n * HD;
    #pragma unroll
    for (int mt = 0; mt < 2; ++mt)
        #pragma unroll
        for (int nt = 0; nt < 4; ++nt)
            #pragma unroll
            for (int r = 0; r < 4; ++r)
                outsp[sOut + (size_t)(i0 + mt * 16 + q * 4 + r) * HD + wave * ODIM + nt * 16 + l16] = acc[mt][nt][r];
    if (l16 == 0) {
        #pragma unroll
        for (int mt = 0; mt < 2; ++mt)
            #pragma unroll
            for (int r = 0; r < 4; ++r)
                densp[((size_t)blockIdx.y * n + i0 + mt * 16 + q * 4 + r) * HEADS + wave] = accd[mt][r];
    }
}

// ============ normalize: out = sum_s outsp / sum_s densp ============
__global__ __launch_bounds__(256) void normalize(const float* __restrict__ outsp,
                                                 const float* __restrict__ densp,
                                                 float* __restrict__ out, int n, int splits) {
    const int g = blockIdx.x * 256 + threadIdx.x;
    const int i = g >> 6;
    const int c4 = (g & 63) * 4;
    const int head = c4 >> 6;
    float den = 0.f;
    for (int s = 0; s < splits; ++s) den += densp[((size_t)s * n + i) * HEADS + head];
    float4 v = {0.f, 0.f, 0.f, 0.f};
    for (int s = 0; s < splits; ++s) {
        const float4 t = *(const float4*)&outsp[(size_t)s * n * HD + (size_t)i * HD + c4];
        v.x += t.x; v.y += t.y; v.z += t.z; v.w += t.w;
    }
    const float inv = 1.0f / den;
    v.x *= inv; v.y *= inv; v.z *= inv; v.w *= inv;
    *(float4*)&out[(size_t)i * HD + c4] = v;
}

extern "C" void kernel_launch(void* const* d_in, const int* in_sizes, int n_in,
                              void* d_out, int out_size, void* d_ws, size_t ws_size,
                              hipStream_t stream) {
    const float* x   = (const float*)d_in[0];
    const int*   adj = (const int*)d_in[1];
    const float* W   = (const float*)d_in[2];
    const float* att = (const float*)d_in[3];
    float* out = (float*)d_out;

    const int in_dim = in_sizes[2] / HD;   // 256
    const int n = in_sizes[0] / in_dim;    // 4096

    char* ws = (char*)d_ws;
    size_t off = 0;
    auto alloc = [&](size_t bytes) -> void* {
        void* p = ws + off; off += (bytes + 255) & ~(size_t)255; return p;
    };
    __hip_bfloat16* xh = (__hip_bfloat16*)alloc((size_t)n * in_dim * 2);
    __hip_bfloat16* xl = (__hip_bfloat16*)alloc((size_t)n * in_dim * 2);
    __hip_bfloat16* wh = (__hip_bfloat16*)alloc((size_t)in_dim * HD * 2);
    __hip_bfloat16* wl = (__hip_bfloat16*)alloc((size_t)in_dim * HD * 2);
    float4*         E4 = (float4*)alloc((size_t)n * HEADS * 16);
    __hip_bfloat16* hbB = (__hip_bfloat16*)alloc((size_t)n * HD * 2);

    const size_t outB = (size_t)n * HD * 4, denB = (size_t)n * HEADS * 4;
    int splits = 1;
    if      (ws_size >= off + 8 * (outB + denB)) splits = 8;
    else if (ws_size >= off + 4 * (outB + denB)) splits = 4;
    else if (ws_size >= off + 2 * (outB + denB)) splits = 2;
    float* densp = (float*)alloc((size_t)splits * denB);
    float* outsp = (splits == 1) ? out : (float*)alloc((size_t)splits * outB);

    pack_x<<<(n / 16) * (in_dim / 32) * 64 / 256, 256, 0, stream>>>(x, xh, xl, in_dim);
    pack_w<<<(HD / 16) * (in_dim / 32) * 64 / 256, 256, 0, stream>>>(W, wh, wl, HD, in_dim);
    gemm_fused<<<dim3(n / 64, HEADS), 256, 0, stream>>>(xh, xl, wh, wl, att, E4, hbB, n, in_dim);
    aggregate<<<dim3(n / 32, splits), 256, 0, stream>>>(adj, E4, hbB, outsp, densp, n, n / splits);
    normalize<<<n * 64 / 256, 256, 0, stream>>>(outsp, densp, out, n, splits);
}

// Round 4
// 147.381 us; speedup vs baseline: 5.0866x; 1.0005x over previous
//
#include <hip/hip_runtime.h>
#include <hip/hip_bf16.h>

#define HEADS 4
#define ODIM 64
#define HD 256          // HEADS*ODIM
#define NEG_SLOPE 0.2f

typedef __attribute__((ext_vector_type(8))) short bf16x8;
typedef __attribute__((ext_vector_type(4))) float floatx4;
typedef __attribute__((ext_vector_type(2))) float floatx2;

// ============ pack x and W -> bf16 hi/lo MFMA fragments (one launch) ============
// A-frag layout: frag[(mc*Kc + kc)][lane][8], lane=(l16,q): A[m=mc*16+l16][k=kc*32+q*8+p]
// B-frag layout: frag[(nc*Kc + kc)][lane][8], lane=(l16,q): B[k=kc*32+q*8+p][n=nc*16+l16]
__global__ __launch_bounds__(256) void pack_xw(const float* __restrict__ x,
                                               const float* __restrict__ W,
                                               __hip_bfloat16* __restrict__ xh,
                                               __hip_bfloat16* __restrict__ xl,
                                               __hip_bfloat16* __restrict__ wh,
                                               __hip_bfloat16* __restrict__ wl,
                                               int K, int nxb) {
    const int b = blockIdx.x;
    const int Kc = K >> 5;
    if (b < nxb) {
        const int g = b * 256 + threadIdx.x;
        const int lane = g & 63, frag = g >> 6;
        const int kc = frag % Kc, mc = frag / Kc;
        const int l16 = lane & 15, q = lane >> 4;
        const float* src = x + (size_t)(mc * 16 + l16) * K + kc * 32 + q * 8;
        const float4 v0 = *(const float4*)src;
        const float4 v1 = *(const float4*)(src + 4);
        const float vv[8] = {v0.x, v0.y, v0.z, v0.w, v1.x, v1.y, v1.z, v1.w};
        union { __hip_bfloat16 b[8]; bf16x8 v; } H, L;
        #pragma unroll
        for (int p = 0; p < 8; ++p) {
            H.b[p] = __float2bfloat16(vv[p]);
            L.b[p] = __float2bfloat16(vv[p] - __bfloat162float(H.b[p]));
        }
        *(bf16x8*)&xh[(size_t)frag * 512 + lane * 8] = H.v;
        *(bf16x8*)&xl[(size_t)frag * 512 + lane * 8] = L.v;
    } else {
        const int g = (b - nxb) * 256 + threadIdx.x;
        const int lane = g & 63, frag = g >> 6;
        const int kc = frag % Kc, nc = frag / Kc;
        const int l16 = lane & 15, q = lane >> 4;
        union { __hip_bfloat16 b[8]; bf16x8 v; } H, L;
        #pragma unroll
        for (int p = 0; p < 8; ++p) {
            const float w = W[(size_t)(kc * 32 + q * 8 + p) * HD + nc * 16 + l16];
            H.b[p] = __float2bfloat16(w);
            L.b[p] = __float2bfloat16(w - __bfloat162float(H.b[p]));
        }
        *(bf16x8*)&wh[(size_t)frag * 512 + lane * 8] = H.v;
        *(bf16x8*)&wl[(size_t)frag * 512 + lane * 8] = L.v;
    }
}

// ============ fused GEMM: h = x@W (hi/lo bf16 MFMA) + E epilogue + B-frag pack of h ============
// block = (64 rows, 1 head). grid (n/64, HEADS).
__global__ __launch_bounds__(256) void gemm_fused(
    const __hip_bfloat16* __restrict__ xh, const __hip_bfloat16* __restrict__ xl,
    const __hip_bfloat16* __restrict__ wh, const __hip_bfloat16* __restrict__ wl,
    const float* __restrict__ att, float4* __restrict__ E4,
    __hip_bfloat16* __restrict__ hbB, int n, int K) {

    __shared__ __hip_bfloat16 T[64][80];   // h^T tile [d][j], stride 80 (16B-aligned rows)

    const int tid = threadIdx.x, wave = tid >> 6, lane = tid & 63;
    const int q = lane >> 4, l16 = lane & 15;
    const int m0 = blockIdx.x * 64;
    const int head = blockIdx.y;
    const int Kc = K >> 5;
    const int mc = (m0 >> 4) + wave;

    floatx4 acc[4] = {{0.f,0.f,0.f,0.f},{0.f,0.f,0.f,0.f},{0.f,0.f,0.f,0.f},{0.f,0.f,0.f,0.f}};

    // fused hi/lo: acc += ah*bh + ah*bl + al*bh   (12 MFMA per kc, 10 loads)
    const __hip_bfloat16* Axh = xh + (size_t)mc * Kc * 512 + lane * 8;
    const __hip_bfloat16* Axl = xl + (size_t)mc * Kc * 512 + lane * 8;
    const __hip_bfloat16* Bwh = wh + lane * 8;
    const __hip_bfloat16* Bwl = wl + lane * 8;
    #pragma unroll 2
    for (int kc = 0; kc < Kc; ++kc) {
        const bf16x8 ah = *(const bf16x8*)(Axh + (size_t)kc * 512);
        const bf16x8 al = *(const bf16x8*)(Axl + (size_t)kc * 512);
        #pragma unroll
        for (int nt = 0; nt < 4; ++nt) {
            const size_t fo = (size_t)((head * 4 + nt) * Kc + kc) * 512;
            const bf16x8 bh = *(const bf16x8*)(Bwh + fo);
            const bf16x8 bl = *(const bf16x8*)(Bwl + fo);
            acc[nt] = __builtin_amdgcn_mfma_f32_16x16x32_bf16(ah, bh, acc[nt], 0, 0, 0);
            acc[nt] = __builtin_amdgcn_mfma_f32_16x16x32_bf16(ah, bl, acc[nt], 0, 0, 0);
            acc[nt] = __builtin_amdgcn_mfma_f32_16x16x32_bf16(al, bh, acc[nt], 0, 0, 0);
        }
    }

    // ---- E epilogue: e_src/e_dst row sums via shuffle over the 16-lane group ----
    float as_v[4], ad_v[4];
    #pragma unroll
    for (int nt = 0; nt < 4; ++nt) {
        as_v[nt] = att[head * 2 * ODIM + nt * 16 + l16];
        ad_v[nt] = att[head * 2 * ODIM + ODIM + nt * 16 + l16];
    }
    #pragma unroll
    for (int r = 0; r < 4; ++r) {
        float ps = 0.f, pd = 0.f;
        #pragma unroll
        for (int nt = 0; nt < 4; ++nt) {
            ps = fmaf(acc[nt][r], as_v[nt], ps);
            pd = fmaf(acc[nt][r], ad_v[nt], pd);
        }
        #pragma unroll
        for (int m = 1; m <= 8; m <<= 1) {
            ps += __shfl_xor(ps, m, 64);
            pd += __shfl_xor(pd, m, 64);
        }
        if (l16 == 0) {
            const int i = m0 + wave * 16 + q * 4 + r;
            E4[i * HEADS + head] = make_float4(__expf(ps), __expf(NEG_SLOPE * ps),
                                               __expf(pd), __expf(NEG_SLOPE * pd));
        }
    }

    // ---- write h tile transposed to LDS as bf16 ----
    #pragma unroll
    for (int nt = 0; nt < 4; ++nt) {
        union { __hip_bfloat16 b[4]; uint2 u; } pk;
        #pragma unroll
        for (int r = 0; r < 4; ++r) pk.b[r] = __float2bfloat16(acc[nt][r]);
        *(uint2*)&T[nt * 16 + l16][wave * 16 + q * 4] = pk.u;
    }
    __syncthreads();

    // ---- emit packed B-frags of h: frag[(head*(n/32) + j32)*4 + nt][lane][8] ----
    #pragma unroll
    for (int ffi = 0; ffi < 2; ++ffi) {
        const int ff = (tid >> 6) + ffi * 4;
        const int kcl = ff >> 2, nt = ff & 3;
        const bf16x8 v = *(const bf16x8*)&T[nt * 16 + l16][kcl * 32 + q * 8];
        const size_t frag = ((size_t)head * (n >> 5) + (m0 >> 5) + kcl) * 4 + nt;
        *(bf16x8*)&hbB[frag * 512 + lane * 8] = v;
    }
}

// ============ aggregate: out_split[s][i][h*64+d] = sum_j P[i,j,h] h[j,h,d] ============
// block: 4 waves (wave=head), i-tile 32, j-chunk 64, K split across blockIdx.y.
// Double-buffered LDS staging: ONE barrier per chunk.
__global__ __launch_bounds__(256, 4) void aggregate(
    const int* __restrict__ adj, const float4* __restrict__ E4,
    const __hip_bfloat16* __restrict__ hbB, float* __restrict__ outsp,
    float* __restrict__ densp, int n, int KR) {

    __shared__ unsigned short adjL[2][32][72];  // stride 72 ushort = 36 dwords (odd-word: conflict-free)
    __shared__ float2 EdL[2][HEADS][64];        // dst-side exps per chunk

    const int tid = threadIdx.x;
    const int wave = tid >> 6, lane = tid & 63;
    const int q = lane >> 4, l16 = lane & 15, q8 = (lane >> 4) * 8;
    const int i0 = blockIdx.x * 32;
    const int K0 = blockIdx.y * KR;

    // staging maps
    const int sr = tid >> 3, sg = (tid & 7) * 8;   // adj: 32 rows x 8-int groups
    const int je = tid >> 2, he = tid & 3;         // E:   64 j x 4 heads

    // src-side exps for this lane's two rows (head = wave), packed for v_pk_mul_f32
    floatx2 es12[2];
    #pragma unroll
    for (int mt = 0; mt < 2; ++mt) {
        const float4 e = E4[(i0 + mt * 16 + l16) * HEADS + wave];
        es12[mt][0] = e.x; es12[mt][1] = e.y;
    }

    // ones-column B-frag for MFMA-based denominator
    union { short s[8]; bf16x8 v; } bones;
    #pragma unroll
    for (int p = 0; p < 8; ++p) bones.s[p] = (l16 == 0) ? (short)0x3F80 : (short)0;

    floatx4 acc[2][4];
    floatx4 accd[2];
    #pragma unroll
    for (int mt = 0; mt < 2; ++mt) {
        accd[mt] = (floatx4){0.f, 0.f, 0.f, 0.f};
        #pragma unroll
        for (int nt = 0; nt < 4; ++nt) acc[mt][nt] = (floatx4){0.f, 0.f, 0.f, 0.f};
    }

    const int* aprow = &adj[(size_t)(i0 + sr) * n];

    // prefetch + stage chunk 0 into buffer 0
    int4 aj0, aj1; float4 ev;
    {
        const int* ap = aprow + K0 + sg;
        aj0 = *(const int4*)ap; aj1 = *(const int4*)(ap + 4);
        ev = E4[(K0 + je) * HEADS + he];
    }
    auto stage = [&](int buf) {
        const int av[8] = {aj0.x, aj0.y, aj0.z, aj0.w, aj1.x, aj1.y, aj1.z, aj1.w};
        uint4 u;
        u.x = (av[0] > 0 ? 0xFFFFu : 0u) | (av[1] > 0 ? 0xFFFF0000u : 0u);
        u.y = (av[2] > 0 ? 0xFFFFu : 0u) | (av[3] > 0 ? 0xFFFF0000u : 0u);
        u.z = (av[4] > 0 ? 0xFFFFu : 0u) | (av[5] > 0 ? 0xFFFF0000u : 0u);
        u.w = (av[6] > 0 ? 0xFFFFu : 0u) | (av[7] > 0 ? 0xFFFF0000u : 0u);
        *(uint4*)&adjL[buf][sr][sg] = u;
        EdL[buf][he][je] = make_float2(ev.z, ev.w);
    };
    stage(0);
    __syncthreads();

    int cur = 0;
    for (int jc = K0; jc < K0 + KR; jc += 64) {
        // ---- prefetch next chunk's adj + E into registers (overlaps compute) ----
        int jn = jc + 64; if (jn >= K0 + KR) jn = K0;   // dummy tail reload
        {
            const int* ap = aprow + jn + sg;
            aj0 = *(const int4*)ap; aj1 = *(const int4*)(ap + 4);
            ev = E4[(jn + je) * HEADS + he];
        }

        // ---- compute from buf[cur] ----
        const size_t kbase = ((size_t)wave * (n >> 5) + (jc >> 5)) * 4;
        #pragma unroll
        for (int ks = 0; ks < 2; ++ks) {
            // B-frags (coalesced, L2-resident)
            bf16x8 bfr[4];
            #pragma unroll
            for (int nt = 0; nt < 4; ++nt)
                bfr[nt] = *(const bf16x8*)&hbB[(kbase + ks * 4 + nt) * 512 + lane * 8];

            const float4* ep = (const float4*)&EdL[cur][wave][ks * 32 + q8];
            const float4 e01 = ep[0], e23 = ep[1], e45 = ep[2], e67 = ep[3];
            floatx2 ed[8];
            ed[0][0]=e01.x; ed[0][1]=e01.y;  ed[1][0]=e01.z; ed[1][1]=e01.w;
            ed[2][0]=e23.x; ed[2][1]=e23.y;  ed[3][0]=e23.z; ed[3][1]=e23.w;
            ed[4][0]=e45.x; ed[4][1]=e45.y;  ed[5][0]=e45.z; ed[5][1]=e45.w;
            ed[6][0]=e67.x; ed[6][1]=e67.y;  ed[7][0]=e67.z; ed[7][1]=e67.w;

            #pragma unroll
            for (int mt = 0; mt < 2; ++mt) {
                const uint4 msk = *(const uint4*)&adjL[cur][mt * 16 + l16][ks * 32 + q8];
                const unsigned int mm[4] = {msk.x, msk.y, msk.z, msk.w};
                union { unsigned int u[4]; bf16x8 v; } af;
                #pragma unroll
                for (int p = 0; p < 4; ++p) {
                    // leaky-relu in exp domain: w = max(es1*edz, es2*edw)  (packed f32 mul)
                    const floatx2 pa = es12[mt] * ed[2 * p];
                    const floatx2 pb = es12[mt] * ed[2 * p + 1];
                    const float wa = fmaxf(pa[0], pa[1]);
                    const float wb = fmaxf(pb[0], pb[1]);
                    // truncation-pack two bf16 in one v_perm_b32, then adjacency mask
                    af.u[p] = __builtin_amdgcn_perm(__float_as_uint(wb), __float_as_uint(wa),
                                                    0x07060302u) & mm[p];
                }
                #pragma unroll
                for (int nt = 0; nt < 4; ++nt)
                    acc[mt][nt] = __builtin_amdgcn_mfma_f32_16x16x32_bf16(af.v, bfr[nt], acc[mt][nt], 0, 0, 0);
                accd[mt] = __builtin_amdgcn_mfma_f32_16x16x32_bf16(af.v, bones.v, accd[mt], 0, 0, 0);
            }
        }

        // ---- stage next chunk into buf[cur^1]; single barrier ----
        stage(cur ^ 1);
        __syncthreads();
        cur ^= 1;
    }

    // ---- epilogue: disjoint per-split writes, no atomics ----
    const size_t sOut = (size_t)blockIdx.y * n * HD;
    #pragma unroll
    for (int mt = 0; mt < 2; ++mt)
        #pragma unroll
        for (int nt = 0; nt < 4; ++nt)
            #pragma unroll
            for (int r = 0; r < 4; ++r)
                outsp[sOut + (size_t)(i0 + mt * 16 + q * 4 + r) * HD + wave * ODIM + nt * 16 + l16] = acc[mt][nt][r];
    if (l16 == 0) {
        #pragma unroll
        for (int mt = 0; mt < 2; ++mt)
            #pragma unroll
            for (int r = 0; r < 4; ++r)
                densp[((size_t)blockIdx.y * n + i0 + mt * 16 + q * 4 + r) * HEADS + wave] = accd[mt][r];
    }
}

// ============ normalize: out = sum_s outsp / sum_s densp ============
__global__ __launch_bounds__(256) void normalize(const float* __restrict__ outsp,
                                                 const float* __restrict__ densp,
                                                 float* __restrict__ out, int n, int splits) {
    const int g = blockIdx.x * 256 + threadIdx.x;
    const int i = g >> 6;
    const int c4 = (g & 63) * 4;
    const int head = c4 >> 6;
    float den = 0.f;
    for (int s = 0; s < splits; ++s) den += densp[((size_t)s * n + i) * HEADS + head];
    float4 v = {0.f, 0.f, 0.f, 0.f};
    for (int s = 0; s < splits; ++s) {
        const float4 t = *(const float4*)&outsp[(size_t)s * n * HD + (size_t)i * HD + c4];
        v.x += t.x; v.y += t.y; v.z += t.z; v.w += t.w;
    }
    const float inv = 1.0f / den;
    v.x *= inv; v.y *= inv; v.z *= inv; v.w *= inv;
    *(float4*)&out[(size_t)i * HD + c4] = v;
}

extern "C" void kernel_launch(void* const* d_in, const int* in_sizes, int n_in,
                              void* d_out, int out_size, void* d_ws, size_t ws_size,
                              hipStream_t stream) {
    const float* x   = (const float*)d_in[0];
    const int*   adj = (const int*)d_in[1];
    const float* W   = (const float*)d_in[2];
    const float* att = (const float*)d_in[3];
    float* out = (float*)d_out;

    const int in_dim = in_sizes[2] / HD;   // 256
    const int n = in_sizes[0] / in_dim;    // 4096

    char* ws = (char*)d_ws;
    size_t off = 0;
    auto alloc = [&](size_t bytes) -> void* {
        void* p = ws + off; off += (bytes + 255) & ~(size_t)255; return p;
    };
    __hip_bfloat16* xh = (__hip_bfloat16*)alloc((size_t)n * in_dim * 2);
    __hip_bfloat16* xl = (__hip_bfloat16*)alloc((size_t)n * in_dim * 2);
    __hip_bfloat16* wh = (__hip_bfloat16*)alloc((size_t)in_dim * HD * 2);
    __hip_bfloat16* wl = (__hip_bfloat16*)alloc((size_t)in_dim * HD * 2);
    float4*         E4 = (float4*)alloc((size_t)n * HEADS * 16);
    __hip_bfloat16* hbB = (__hip_bfloat16*)alloc((size_t)n * HD * 2);

    const size_t outB = (size_t)n * HD * 4, denB = (size_t)n * HEADS * 4;
    int splits = 1;
    if      (ws_size >= off + 8 * (outB + denB)) splits = 8;
    else if (ws_size >= off + 4 * (outB + denB)) splits = 4;
    else if (ws_size >= off + 2 * (outB + denB)) splits = 2;
    float* densp = (float*)alloc((size_t)splits * denB);
    float* outsp = (splits == 1) ? out : (float*)alloc((size_t)splits * outB);

    const int nxb = (n / 16) * (in_dim / 32) * 64 / 256;
    const int nwb = (HD / 16) * (in_dim / 32) * 64 / 256;
    pack_xw<<<nxb + nwb, 256, 0, stream>>>(x, W, xh, xl, wh, wl, in_dim, nxb);
    gemm_fused<<<dim3(n / 64, HEADS), 256, 0, stream>>>(xh, xl, wh, wl, att, E4, hbB, n, in_dim);
    aggregate<<<dim3(n / 32, splits), 256, 0, stream>>>(adj, E4, hbB, outsp, densp, n, n / splits);
    normalize<<<n * 64 / 256, 256, 0, stream>>>(outsp, densp, out, n, splits);
}

// Round 5
// 143.619 us; speedup vs baseline: 5.2199x; 1.0262x over previous
//
#include <hip/hip_runtime.h>
#include <hip/hip_bf16.h>

#define HEADS 4
#define ODIM 64
#define HD 256          // HEADS*ODIM
#define NEG_SLOPE 0.2f
#define SPLITS 4
#define BJ 128          // j-chunk

typedef __attribute__((ext_vector_type(8))) short bf16x8;
typedef __attribute__((ext_vector_type(4))) float floatx4;
typedef __attribute__((ext_vector_type(2))) float floatx2;

// ============ pack x and W -> bf16 hi/lo MFMA fragments (one launch) ============
// A-frag layout: frag[(mc*Kc + kc)][lane][8], lane=(l16,q): A[m=mc*16+l16][k=kc*32+q*8+p]
// B-frag layout: frag[(nc*Kc + kc)][lane][8], lane=(l16,q): B[k=kc*32+q*8+p][n=nc*16+l16]
__global__ __launch_bounds__(256) void pack_xw(const float* __restrict__ x,
                                               const float* __restrict__ W,
                                               __hip_bfloat16* __restrict__ xh,
                                               __hip_bfloat16* __restrict__ xl,
                                               __hip_bfloat16* __restrict__ wh,
                                               __hip_bfloat16* __restrict__ wl,
                                               int K, int nxb) {
    const int b = blockIdx.x;
    const int Kc = K >> 5;
    if (b < nxb) {
        const int g = b * 256 + threadIdx.x;
        const int lane = g & 63, frag = g >> 6;
        const int kc = frag % Kc, mc = frag / Kc;
        const int l16 = lane & 15, q = lane >> 4;
        const float* src = x + (size_t)(mc * 16 + l16) * K + kc * 32 + q * 8;
        const float4 v0 = *(const float4*)src;
        const float4 v1 = *(const float4*)(src + 4);
        const float vv[8] = {v0.x, v0.y, v0.z, v0.w, v1.x, v1.y, v1.z, v1.w};
        union { __hip_bfloat16 b[8]; bf16x8 v; } H, L;
        #pragma unroll
        for (int p = 0; p < 8; ++p) {
            H.b[p] = __float2bfloat16(vv[p]);
            L.b[p] = __float2bfloat16(vv[p] - __bfloat162float(H.b[p]));
        }
        *(bf16x8*)&xh[(size_t)frag * 512 + lane * 8] = H.v;
        *(bf16x8*)&xl[(size_t)frag * 512 + lane * 8] = L.v;
    } else {
        const int g = (b - nxb) * 256 + threadIdx.x;
        const int lane = g & 63, frag = g >> 6;
        const int kc = frag % Kc, nc = frag / Kc;
        const int l16 = lane & 15, q = lane >> 4;
        union { __hip_bfloat16 b[8]; bf16x8 v; } H, L;
        #pragma unroll
        for (int p = 0; p < 8; ++p) {
            const float w = W[(size_t)(kc * 32 + q * 8 + p) * HD + nc * 16 + l16];
            H.b[p] = __float2bfloat16(w);
            L.b[p] = __float2bfloat16(w - __bfloat162float(H.b[p]));
        }
        *(bf16x8*)&wh[(size_t)frag * 512 + lane * 8] = H.v;
        *(bf16x8*)&wl[(size_t)frag * 512 + lane * 8] = L.v;
    }
}

// ============ fused GEMM: h = x@W (hi/lo bf16 MFMA) + E epilogue + B-frag pack of h ============
// block = 128 thr (2 waves, 16 rows each), grid (n/32, HEADS) = 512 blocks (2/CU).
__global__ __launch_bounds__(128) void gemm_fused(
    const __hip_bfloat16* __restrict__ xh, const __hip_bfloat16* __restrict__ xl,
    const __hip_bfloat16* __restrict__ wh, const __hip_bfloat16* __restrict__ wl,
    const float* __restrict__ att, float4* __restrict__ E4,
    __hip_bfloat16* __restrict__ hbB, int n, int K) {

    __shared__ __hip_bfloat16 T[64][40];   // h^T tile [d][j(32)], stride 40 (16B-aligned rows)

    const int tid = threadIdx.x, wave = tid >> 6, lane = tid & 63;
    const int q = lane >> 4, l16 = lane & 15;
    const int m0 = blockIdx.x * 32;
    const int head = blockIdx.y;
    const int Kc = K >> 5;
    const int mc = (m0 >> 4) + wave;

    floatx4 acc[4] = {{0.f,0.f,0.f,0.f},{0.f,0.f,0.f,0.f},{0.f,0.f,0.f,0.f},{0.f,0.f,0.f,0.f}};

    const __hip_bfloat16* Axh = xh + (size_t)mc * Kc * 512 + lane * 8;
    const __hip_bfloat16* Axl = xl + (size_t)mc * Kc * 512 + lane * 8;
    const __hip_bfloat16* Bwh = wh + lane * 8;
    const __hip_bfloat16* Bwl = wl + lane * 8;
    #pragma unroll 2
    for (int kc = 0; kc < Kc; ++kc) {
        const bf16x8 ah = *(const bf16x8*)(Axh + (size_t)kc * 512);
        const bf16x8 al = *(const bf16x8*)(Axl + (size_t)kc * 512);
        bf16x8 bh[4], bl[4];
        #pragma unroll
        for (int nt = 0; nt < 4; ++nt) {
            const size_t fo = (size_t)((head * 4 + nt) * Kc + kc) * 512;
            bh[nt] = *(const bf16x8*)(Bwh + fo);
            bl[nt] = *(const bf16x8*)(Bwl + fo);
        }
        // pass-major order: dependency distance 4 between same-acc MFMAs
        #pragma unroll
        for (int nt = 0; nt < 4; ++nt)
            acc[nt] = __builtin_amdgcn_mfma_f32_16x16x32_bf16(ah, bh[nt], acc[nt], 0, 0, 0);
        #pragma unroll
        for (int nt = 0; nt < 4; ++nt)
            acc[nt] = __builtin_amdgcn_mfma_f32_16x16x32_bf16(ah, bl[nt], acc[nt], 0, 0, 0);
        #pragma unroll
        for (int nt = 0; nt < 4; ++nt)
            acc[nt] = __builtin_amdgcn_mfma_f32_16x16x32_bf16(al, bh[nt], acc[nt], 0, 0, 0);
    }

    // ---- E epilogue: e_src/e_dst row sums via shuffle over the 16-lane group ----
    float as_v[4], ad_v[4];
    #pragma unroll
    for (int nt = 0; nt < 4; ++nt) {
        as_v[nt] = att[head * 2 * ODIM + nt * 16 + l16];
        ad_v[nt] = att[head * 2 * ODIM + ODIM + nt * 16 + l16];
    }
    #pragma unroll
    for (int r = 0; r < 4; ++r) {
        float ps = 0.f, pd = 0.f;
        #pragma unroll
        for (int nt = 0; nt < 4; ++nt) {
            ps = fmaf(acc[nt][r], as_v[nt], ps);
            pd = fmaf(acc[nt][r], ad_v[nt], pd);
        }
        #pragma unroll
        for (int m = 1; m <= 8; m <<= 1) {
            ps += __shfl_xor(ps, m, 64);
            pd += __shfl_xor(pd, m, 64);
        }
        if (l16 == 0) {
            const int i = m0 + wave * 16 + q * 4 + r;
            E4[i * HEADS + head] = make_float4(__expf(ps), __expf(NEG_SLOPE * ps),
                                               __expf(pd), __expf(NEG_SLOPE * pd));
        }
    }

    // ---- write h tile transposed to LDS as bf16 ----
    #pragma unroll
    for (int nt = 0; nt < 4; ++nt) {
        union { __hip_bfloat16 b[4]; uint2 u; } pk;
        #pragma unroll
        for (int r = 0; r < 4; ++r) pk.b[r] = __float2bfloat16(acc[nt][r]);
        *(uint2*)&T[nt * 16 + l16][wave * 16 + q * 4] = pk.u;
    }
    __syncthreads();

    // ---- emit packed B-frags of h: frag[(head*(n/32) + j32)*4 + nt][lane][8] ----
    #pragma unroll
    for (int ffi = 0; ffi < 2; ++ffi) {
        const int f = wave + ffi * 2;   // nt
        const bf16x8 v = *(const bf16x8*)&T[f * 16 + l16][q * 8];
        const size_t frag = ((size_t)head * (n >> 5) + (m0 >> 5)) * 4 + f;
        *(bf16x8*)&hbB[frag * 512 + lane * 8] = v;
    }
}

// ============ aggregate: out_split[s][i][h*64+d] = sum_j P[i,j,h] h[j,h,d] ============
// block: 4 waves (wave=head), i-tile 32, j-chunk 128, K split 4-way.
// Depth-2 adj/E register prefetch; per-ks B-frag software pipeline; dbuf LDS.
__global__ __launch_bounds__(256, 2) void aggregate(
    const int* __restrict__ adj, const float4* __restrict__ E4,
    const __hip_bfloat16* __restrict__ hbB, float* __restrict__ outsp,
    float* __restrict__ densp, int n, int KR) {

    __shared__ unsigned short adjL[2][32][136];  // masks; stride 136 ush = 68 dw (balanced b128 banks)
    __shared__ float2 EdL[2][HEADS][BJ];         // dst-side exps per chunk

    const int tid = threadIdx.x;
    const int wave = tid >> 6, lane = tid & 63;
    const int q = lane >> 4, l16 = lane & 15, q8 = (lane >> 4) * 8;
    const int i0 = blockIdx.x * 32;
    const int K0 = blockIdx.y * KR;

    // staging maps
    const int sr = tid >> 3, sg = (tid & 7) * 16;  // adj: 32 rows x 16-int groups
    const int je = tid >> 1, heb = (tid & 1) * 2;  // E: 128 j x 2 head-pairs

    // src-side exps for this lane's two rows (head = wave)
    floatx2 es12[2];
    #pragma unroll
    for (int mt = 0; mt < 2; ++mt) {
        const float4 e = E4[(i0 + mt * 16 + l16) * HEADS + wave];
        es12[mt][0] = e.x; es12[mt][1] = e.y;
    }

    // ones-column B-frag for MFMA-based denominator
    union { short s[8]; bf16x8 v; } bones;
    #pragma unroll
    for (int p = 0; p < 8; ++p) bones.s[p] = (l16 == 0) ? (short)0x3F80 : (short)0;

    floatx4 acc[2][4];
    floatx4 accd[2];
    #pragma unroll
    for (int mt = 0; mt < 2; ++mt) {
        accd[mt] = (floatx4){0.f, 0.f, 0.f, 0.f};
        #pragma unroll
        for (int nt = 0; nt < 4; ++nt) acc[mt][nt] = (floatx4){0.f, 0.f, 0.f, 0.f};
    }

    const int* aprow = &adj[(size_t)(i0 + sr) * n];
    const size_t fragbase = (size_t)wave * (n >> 5) * 4;   // hbB frag base for this head

    int4 ajA[4], ajB[4];
    float4 evA0, evA1, evB0, evB1;

    auto loadPref = [&](int jc, int4* aj, float4& e0, float4& e1) {
        const int4* ap = (const int4*)(aprow + jc + sg);
        aj[0] = ap[0]; aj[1] = ap[1]; aj[2] = ap[2]; aj[3] = ap[3];
        e0 = E4[(jc + je) * HEADS + heb];
        e1 = E4[(jc + je) * HEADS + heb + 1];
    };
    auto stage = [&](int buf, const int4* aj, const float4& e0, const float4& e1) {
        const int* av = (const int*)aj;
        #pragma unroll
        for (int g2 = 0; g2 < 2; ++g2) {
            uint4 u;
            u.x = (av[g2*8+0] > 0 ? 0xFFFFu : 0u) | (av[g2*8+1] > 0 ? 0xFFFF0000u : 0u);
            u.y = (av[g2*8+2] > 0 ? 0xFFFFu : 0u) | (av[g2*8+3] > 0 ? 0xFFFF0000u : 0u);
            u.z = (av[g2*8+4] > 0 ? 0xFFFFu : 0u) | (av[g2*8+5] > 0 ? 0xFFFF0000u : 0u);
            u.w = (av[g2*8+6] > 0 ? 0xFFFFu : 0u) | (av[g2*8+7] > 0 ? 0xFFFF0000u : 0u);
            *(uint4*)&adjL[buf][sr][sg + g2 * 8] = u;
        }
        EdL[buf][heb][je]     = make_float2(e0.z, e0.w);
        EdL[buf][heb + 1][je] = make_float2(e1.z, e1.w);
    };

    auto computeChunk = [&](int buf, int jc) {
        bf16x8 bA[4], bB[4];
        #pragma unroll
        for (int nt = 0; nt < 4; ++nt)
            bA[nt] = *(const bf16x8*)&hbB[(fragbase + (size_t)(jc >> 5) * 4 + nt) * 512 + lane * 8];
        #pragma unroll
        for (int ks = 0; ks < 4; ++ks) {
            const bf16x8* bcur = (ks & 1) ? bB : bA;
            bf16x8* bnxt = (ks & 1) ? bA : bB;
            if (ks < 3) {   // prefetch next ks while computing this one
                #pragma unroll
                for (int nt = 0; nt < 4; ++nt)
                    bnxt[nt] = *(const bf16x8*)&hbB[(fragbase + (size_t)((jc >> 5) + ks + 1) * 4 + nt) * 512 + lane * 8];
            }
            const float4* ep = (const float4*)&EdL[buf][wave][ks * 32 + q8];
            const float4 e01 = ep[0], e23 = ep[1], e45 = ep[2], e67 = ep[3];
            floatx2 ed[8];
            ed[0][0]=e01.x; ed[0][1]=e01.y;  ed[1][0]=e01.z; ed[1][1]=e01.w;
            ed[2][0]=e23.x; ed[2][1]=e23.y;  ed[3][0]=e23.z; ed[3][1]=e23.w;
            ed[4][0]=e45.x; ed[4][1]=e45.y;  ed[5][0]=e45.z; ed[5][1]=e45.w;
            ed[6][0]=e67.x; ed[6][1]=e67.y;  ed[7][0]=e67.z; ed[7][1]=e67.w;
            #pragma unroll
            for (int mt = 0; mt < 2; ++mt) {
                const uint4 msk = *(const uint4*)&adjL[buf][mt * 16 + l16][ks * 32 + q8];
                const unsigned int mm[4] = {msk.x, msk.y, msk.z, msk.w};
                union { unsigned int u[4]; bf16x8 v; } af;
                #pragma unroll
                for (int p = 0; p < 4; ++p) {
                    const floatx2 pa = es12[mt] * ed[2 * p];
                    const floatx2 pb = es12[mt] * ed[2 * p + 1];
                    const float wa = fmaxf(pa[0], pa[1]);   // leaky-relu in exp domain
                    const float wb = fmaxf(pb[0], pb[1]);
                    af.u[p] = __builtin_amdgcn_perm(__float_as_uint(wb), __float_as_uint(wa),
                                                    0x07060302u) & mm[p];
                }
                #pragma unroll
                for (int nt = 0; nt < 4; ++nt)
                    acc[mt][nt] = __builtin_amdgcn_mfma_f32_16x16x32_bf16(af.v, bcur[nt], acc[mt][nt], 0, 0, 0);
                accd[mt] = __builtin_amdgcn_mfma_f32_16x16x32_bf16(af.v, bones.v, accd[mt], 0, 0, 0);
            }
        }
    };

    // ---- prologue: chunks 0,1 into reg sets A,B; stage chunk0 -> buf0 ----
    const int KEND = K0 + KR;
    loadPref(K0, ajA, evA0, evA1);
    loadPref(K0 + BJ < KEND ? K0 + BJ : K0, ajB, evB0, evB1);
    stage(0, ajA, evA0, evA1);
    __syncthreads();

    // ---- main loop, 2 chunks per iteration (KR/BJ is even: 1024/128 = 8) ----
    for (int jc = K0; jc < KEND; jc += 2 * BJ) {
        int j2 = jc + 2 * BJ; if (j2 >= KEND) j2 = K0;
        loadPref(j2, ajA, evA0, evA1);          // chunk c+2 -> set A
        computeChunk(0, jc);                     // chunk c from buf0
        stage(1, ajB, evB0, evB1);               // chunk c+1 -> buf1
        __syncthreads();

        int j3 = jc + 3 * BJ; if (j3 >= KEND) j3 = K0;
        loadPref(j3, ajB, evB0, evB1);          // chunk c+3 -> set B
        computeChunk(1, jc + BJ);                // chunk c+1 from buf1
        stage(0, ajA, evA0, evA1);               // chunk c+2 -> buf0
        __syncthreads();
    }

    // ---- epilogue: disjoint per-split writes, no atomics ----
    const size_t sOut = (size_t)blockIdx.y * n * HD;
    #pragma unroll
    for (int mt = 0; mt < 2; ++mt)
        #pragma unroll
        for (int nt = 0; nt < 4; ++nt)
            #pragma unroll
            for (int r = 0; r < 4; ++r)
                outsp[sOut + (size_t)(i0 + mt * 16 + q * 4 + r) * HD + wave * ODIM + nt * 16 + l16] = acc[mt][nt][r];
    if (l16 == 0) {
        #pragma unroll
        for (int mt = 0; mt < 2; ++mt)
            #pragma unroll
            for (int r = 0; r < 4; ++r)
                densp[((size_t)blockIdx.y * n + i0 + mt * 16 + q * 4 + r) * HEADS + wave] = accd[mt][r];
    }
}

// ============ normalize: out = sum_s outsp / sum_s densp ============
__global__ __launch_bounds__(256) void normalize(const float* __restrict__ outsp,
                                                 const float* __restrict__ densp,
                                                 float* __restrict__ out, int n, int splits) {
    const int g = blockIdx.x * 256 + threadIdx.x;
    const int i = g >> 6;
    const int c4 = (g & 63) * 4;
    const int head = c4 >> 6;
    float den = 0.f;
    for (int s = 0; s < splits; ++s) den += densp[((size_t)s * n + i) * HEADS + head];
    float4 v = {0.f, 0.f, 0.f, 0.f};
    for (int s = 0; s < splits; ++s) {
        const float4 t = *(const float4*)&outsp[(size_t)s * n * HD + (size_t)i * HD + c4];
        v.x += t.x; v.y += t.y; v.z += t.z; v.w += t.w;
    }
    const float inv = 1.0f / den;
    v.x *= inv; v.y *= inv; v.z *= inv; v.w *= inv;
    *(float4*)&out[(size_t)i * HD + c4] = v;
}

extern "C" void kernel_launch(void* const* d_in, const int* in_sizes, int n_in,
                              void* d_out, int out_size, void* d_ws, size_t ws_size,
                              hipStream_t stream) {
    const float* x   = (const float*)d_in[0];
    const int*   adj = (const int*)d_in[1];
    const float* W   = (const float*)d_in[2];
    const float* att = (const float*)d_in[3];
    float* out = (float*)d_out;

    const int in_dim = in_sizes[2] / HD;   // 256
    const int n = in_sizes[0] / in_dim;    // 4096

    char* ws = (char*)d_ws;
    size_t off = 0;
    auto alloc = [&](size_t bytes) -> void* {
        void* p = ws + off; off += (bytes + 255) & ~(size_t)255; return p;
    };
    __hip_bfloat16* xh = (__hip_bfloat16*)alloc((size_t)n * in_dim * 2);
    __hip_bfloat16* xl = (__hip_bfloat16*)alloc((size_t)n * in_dim * 2);
    __hip_bfloat16* wh = (__hip_bfloat16*)alloc((size_t)in_dim * HD * 2);
    __hip_bfloat16* wl = (__hip_bfloat16*)alloc((size_t)in_dim * HD * 2);
    float4*         E4 = (float4*)alloc((size_t)n * HEADS * 16);
    __hip_bfloat16* hbB = (__hip_bfloat16*)alloc((size_t)n * HD * 2);

    const size_t outB = (size_t)n * HD * 4, denB = (size_t)n * HEADS * 4;
    float* densp = (float*)alloc((size_t)SPLITS * denB);
    float* outsp = (float*)alloc((size_t)SPLITS * outB);

    const int nxb = (n / 16) * (in_dim / 32) * 64 / 256;
    const int nwb = (HD / 16) * (in_dim / 32) * 64 / 256;
    pack_xw<<<nxb + nwb, 256, 0, stream>>>(x, W, xh, xl, wh, wl, in_dim, nxb);
    gemm_fused<<<dim3(n / 32, HEADS), 128, 0, stream>>>(xh, xl, wh, wl, att, E4, hbB, n, in_dim);
    aggregate<<<dim3(n / 32, SPLITS), 256, 0, stream>>>(adj, E4, hbB, outsp, densp, n, n / SPLITS);
    normalize<<<n * 64 / 256, 256, 0, stream>>>(outsp, densp, out, n, SPLITS);
}